// Round 16
// baseline (438.529 us; speedup 1.0000x reference)
//
#include <hip/hip_runtime.h>

#define N_NODES 50000
#define E_EDGES 640000
#define D 128
#define DS 64
#define NTILES 3125   // 50000 / 16 exactly
#define BUCKET 64     // max degree capacity (Poisson(12.8): P(>64) ~ 0)
#define CPAD 16       // one cursor counter per 64B line
#define NPART 8       // dst-range partitions (~XCDs)
#define PSIZE 6250    // N_NODES / NPART
#define BCAP  98304   // per-partition bin capacity (~80k expected)

typedef __bf16 bf16x8 __attribute__((ext_vector_type(8)));
typedef float f32x4 __attribute__((ext_vector_type(4)));

static __device__ __forceinline__ ushort f2bf(float f) {
    uint u = __float_as_uint(f);
    uint r = u + 0x7fffu + ((u >> 16) & 1u);
    return (ushort)(r >> 16);
}

// ---------------- prep: zero cursor/bincnt + x->bf16 + weight transposes ----------------
// Fragment-major weight layouts.
// WTf: fragment (f=n/16, s=k/32): F=f*8+s; lane l=(n&15)|(((k>>3)&3)<<4);
//      (n,k) -> WTf[(F*64+l)*8+(k&7)].  WsTf: F=(m>>4)*4+(k>>5), same inner.

__global__ void prep_kernel(const float* __restrict__ x,
                            const float* __restrict__ Wl1, const float* __restrict__ Wr1,
                            const float* __restrict__ Wl2, const float* __restrict__ Wr2,
                            const float* __restrict__ Ws,
                            int* __restrict__ cursor, int* __restrict__ bincnt,
                            ushort* __restrict__ xb,
                            ushort* __restrict__ WT1f, ushort* __restrict__ WT2f,
                            ushort* __restrict__ WsTf) {
    int tid = blockIdx.x * blockDim.x + threadIdx.x;
    int stride = gridDim.x * blockDim.x;
    for (int i = tid; i < N_NODES * CPAD; i += stride) cursor[i] = 0;
    if (tid < NPART * 16) bincnt[tid] = 0;
    if (tid < 32768) {
        int n = tid >> 8, k = tid & 255;
        float v = (k < 128) ? Wl1[k * 128 + n] : Wr1[(k - 128) * 128 + n];
        int F = (n >> 4) * 8 + (k >> 5);
        int l = (n & 15) | (((k >> 3) & 3) << 4);
        WT1f[(F * 64 + l) * 8 + (k & 7)] = f2bf(v);
    } else if (tid < 65536) {
        int j = tid - 32768;
        int n = j >> 8, k = j & 255;
        float v = (k < 128) ? Wl2[k * 128 + n] : Wr2[(k - 128) * 128 + n];
        int F = (n >> 4) * 8 + (k >> 5);
        int l = (n & 15) | (((k >> 3) & 3) << 4);
        WT2f[(F * 64 + l) * 8 + (k & 7)] = f2bf(v);
    } else if (tid < 73728) {
        int j = tid - 65536;
        int m = j >> 7, k = j & 127;
        int F = (m >> 4) * 4 + (k >> 5);
        int l = (m & 15) | (((k >> 3) & 3) << 4);
        WsTf[(F * 64 + l) * 8 + (k & 7)] = f2bf(Ws[k * 64 + m]);
    }
    const int n4 = N_NODES * D / 4;
    for (int i = tid; i < n4; i += stride) {
        float4 v = ((const float4*)x)[i];
        ushort4 o;
        o.x = f2bf(v.x); o.y = f2bf(v.y); o.z = f2bf(v.z); o.w = f2bf(v.w);
        ((ushort4*)xb)[i] = o;
    }
}

// ---------------- pass 1: wave-aggregated dst-partition binning ----------------
// Packs (dst<<16)|src into binned[p]; writes are wave-clustered (~8 contiguous
// entries per wave per partition) and each edge is written ONCE -> ~2.6 MB.

__global__ void bin_pass(const int* __restrict__ src, const int* __restrict__ dst,
                         int* __restrict__ bincnt, uint* __restrict__ binned, int e) {
    int lane = threadIdx.x & 63;
    int i = blockIdx.x * blockDim.x + threadIdx.x;
    int stride = gridDim.x * blockDim.x;
    for (; i < e; i += stride) {
        int d = dst[i];
        int s = src[i];
        int myp = d / PSIZE;                  // 0..7
        uint entry = ((uint)d << 16) | (uint)s;
#pragma unroll
        for (int p = 0; p < NPART; ++p) {
            unsigned long long mask = __ballot(myp == p);
            if (mask) {
                int leader = __ffsll((long long)mask) - 1;
                int cnt = __popcll(mask);
                int base = 0;
                if (lane == leader) base = atomicAdd(&bincnt[p * 16], cnt);
                base = __shfl(base, leader);
                int rank = __popcll(mask & ((1ull << lane) - 1ull));
                int slot = base + rank;
                if (myp == p && slot < BCAP) binned[(size_t)p * BCAP + slot] = entry;
            }
        }
    }
}

// ---------------- pass 2: per-partition scatter (L2-resident working set) ----------------
// Group g = blockIdx&7 (round-robin ~XCD) reads ONLY its ~320 KB bin; working set
// (esrc 800KB + cursor 400KB + stream) fits one L2 -> bucket lines write back once.

__global__ void scatter_pass(const uint* __restrict__ binned, const int* __restrict__ bincnt,
                             int* __restrict__ cursor, ushort* __restrict__ esrc) {
    int g = blockIdx.x & (NPART - 1);
    int bchunk = blockIdx.x >> 3;
    int nb = gridDim.x >> 3;
    int n = bincnt[g * 16]; if (n > BCAP) n = BCAP;
    int i = bchunk * blockDim.x + threadIdx.x;
    int stride = nb * blockDim.x;
    const uint* bin = binned + (size_t)g * BCAP;
    for (; i < n; i += stride) {
        uint e = bin[i];
        int d = (int)(e >> 16);
        int s = (int)(e & 0xffffu);
        int pos = atomicAdd(&cursor[d * CPAD], 1);
        if (pos < BUCKET) esrc[d * BUCKET + pos] = (ushort)s;
    }
}

// ---------------- segment mean, bf16 in/out ----------------
// one wave per dst node (50k waves -> max gather TLP); 16 lanes x 16B cover a
// 256B row; 16 edges in flight per iter

__global__ void aggregate_mean_bf16(const ushort* __restrict__ feat, const int* __restrict__ cursor,
                                    const ushort* __restrict__ esrc, ushort* __restrict__ mean, int n) {
    int wid = threadIdx.x >> 6;           // 4 waves per block
    int lane = threadIdx.x & 63;
    int d = blockIdx.x * 4 + wid;
    if (d >= n) return;
    int cnt = cursor[d * CPAD]; if (cnt > BUCKET) cnt = BUCKET;
    int beg = d * BUCKET;
    int g = lane >> 4;                    // edge group 0..3
    int gl = lane & 15;                   // 16B chunk within row

    float acc[8] = {0.f, 0.f, 0.f, 0.f, 0.f, 0.f, 0.f, 0.f};
    for (int i = 0; i < cnt; i += 16) {
        uint4 v[4];
#pragma unroll
        for (int j = 0; j < 4; ++j) {
            int idx = i + g + j * 4;
            v[j] = make_uint4(0u, 0u, 0u, 0u);
            if (idx < cnt) {
                int e = esrc[beg + idx];
                v[j] = ((const uint4*)(feat + (size_t)e * D))[gl];
            }
        }
#pragma unroll
        for (int j = 0; j < 4; ++j) {
            acc[0] += __uint_as_float(v[j].x << 16);
            acc[1] += __uint_as_float(v[j].x & 0xffff0000u);
            acc[2] += __uint_as_float(v[j].y << 16);
            acc[3] += __uint_as_float(v[j].y & 0xffff0000u);
            acc[4] += __uint_as_float(v[j].z << 16);
            acc[5] += __uint_as_float(v[j].z & 0xffff0000u);
            acc[6] += __uint_as_float(v[j].w << 16);
            acc[7] += __uint_as_float(v[j].w & 0xffff0000u);
        }
    }
#pragma unroll
    for (int m = 16; m <= 32; m <<= 1) {
#pragma unroll
        for (int j = 0; j < 8; ++j) acc[j] += __shfl_xor(acc[j], m);
    }
    if (g == 0) {
        float inv = (cnt > 0) ? 1.0f / (float)cnt : 0.0f;
        uint4 o;
        o.x = (uint)f2bf(acc[0] * inv) | ((uint)f2bf(acc[1] * inv) << 16);
        o.y = (uint)f2bf(acc[2] * inv) | ((uint)f2bf(acc[3] * inv) << 16);
        o.z = (uint)f2bf(acc[4] * inv) | ((uint)f2bf(acc[5] * inv) << 16);
        o.w = (uint)f2bf(acc[6] * inv) | ((uint)f2bf(acc[7] * inv) << 16);
        ((uint4*)(mean + (size_t)d * D))[gl] = o;
    }
}

// ---------------- fused SAGE MFMA GEMM: C = [mean|self] @ WT^T + b ----------------
// ONE 16-row tile per wave (no loop, no prefetch -> no spill).
// Swapped operands: mfma(W_frag, Act_frag) -> lane&15 = node, quad = feature.
// Lane's f32x4 acc is feature-contiguous -> 16B f32 / 8B bf16 stores.
// OUTS: fuse out_s = h2 @ Ws via convergent-shfl redistribution + Ws frags in LDS.

template <bool RELU, bool WF32, bool WBF16, bool OUTS>
__global__ __launch_bounds__(512) void sage_mfma(
    const ushort* __restrict__ A1, const ushort* __restrict__ A2,
    const ushort* __restrict__ WTf, const float* __restrict__ bias,
    float* __restrict__ Hf, ushort* __restrict__ Hb,
    const ushort* __restrict__ WsTf, float* __restrict__ OutS)
{
    __shared__ __attribute__((aligned(16))) char smem[OUTS ? 81920 : 65536];
    int w = threadIdx.x >> 6, lane = threadIdx.x & 63;

    // stage WTf linearly (64 KB, fragment-major; dest = uniform base + lane*16)
#pragma unroll
    for (int it = 0; it < 8; ++it) {
        int off = w * 8192 + it * 1024;
        __builtin_amdgcn_global_load_lds(
            (const __attribute__((address_space(1))) void*)((const char*)WTf + off + lane * 16),
            (__attribute__((address_space(3))) void*)(smem + off), 16, 0, 0);
    }
    if (OUTS) {   // stage WsTf (16 KB) at smem+65536
#pragma unroll
        for (int it = 0; it < 2; ++it) {
            int off = w * 2048 + it * 1024;
            __builtin_amdgcn_global_load_lds(
                (const __attribute__((address_space(1))) void*)((const char*)WsTf + off + lane * 16),
                (__attribute__((address_space(3))) void*)(smem + 65536 + off), 16, 0, 0);
        }
    }

    int rl = lane & 15;       // node within tile
    int kg = lane >> 4;       // k-subgroup / feature quad
    int tile = blockIdx.x * 8 + w;

    bf16x8 a[8];
    if (tile < NTILES) {
        const ushort* r1 = A1 + (size_t)(tile * 16 + rl) * 128 + kg * 8;
        const ushort* r2 = A2 + (size_t)(tile * 16 + rl) * 128 + kg * 8;
#pragma unroll
        for (int s = 0; s < 4; ++s) a[s] = *reinterpret_cast<const bf16x8*>(r1 + s * 32);
#pragma unroll
        for (int s = 0; s < 4; ++s) a[4 + s] = *reinterpret_cast<const bf16x8*>(r2 + s * 32);
    }
    __syncthreads();          // staging visible to all waves
    if (tile >= NTILES) return;

    // acc init = bias (broadcast over nodes; lane's features f*16+kg*4..+3)
    f32x4 acc[8];
#pragma unroll
    for (int f = 0; f < 8; ++f)
        acc[f] = *reinterpret_cast<const f32x4*>(bias + f * 16 + kg * 4);

#pragma unroll
    for (int s = 0; s < 8; ++s) {
#pragma unroll
        for (int f = 0; f < 8; ++f) {
            bf16x8 b = *reinterpret_cast<const bf16x8*>(smem + ((f * 8 + s) * 64 + lane) * 16);
            acc[f] = __builtin_amdgcn_mfma_f32_16x16x32_bf16(b, a[s], acc[f], 0, 0, 0);
        }
    }

    int node = tile * 16 + rl;
    // epilogue: lane holds features n = f*16 + kg*4 + (0..3) of `node`
#pragma unroll
    for (int f = 0; f < 8; ++f) {
        f32x4 v = acc[f];
        if (RELU) {
            v[0] = fmaxf(v[0], 0.f); v[1] = fmaxf(v[1], 0.f);
            v[2] = fmaxf(v[2], 0.f); v[3] = fmaxf(v[3], 0.f);
        }
        acc[f] = v;
        size_t o = (size_t)node * 128 + f * 16 + kg * 4;
        if (WF32)
            *reinterpret_cast<f32x4*>(Hf + o) = v;
        if (WBF16) {
            ushort4 ob;
            ob.x = f2bf(v[0]); ob.y = f2bf(v[1]); ob.z = f2bf(v[2]); ob.w = f2bf(v[3]);
            *reinterpret_cast<ushort4*>(Hb + o) = ob;
        }
    }

    if (OUTS) {
        // lane holds bf16(h2) features f*16+kg*4..+3 packed: abx=(e0,e1), aby=(e2,e3)
        uint abx[8], aby[8];
#pragma unroll
        for (int f = 0; f < 8; ++f) {
            abx[f] = (uint)f2bf(acc[f][0]) | ((uint)f2bf(acc[f][1]) << 16);
            aby[f] = (uint)f2bf(acc[f][2]) | ((uint)f2bf(acc[f][3]) << 16);
        }
        int sbase = rl + ((lane & 16) << 1);   // rl + (kg&1)*32
        bool top = lane >= 32;                 // kg>>1
        f32x4 accO[4];
#pragma unroll
        for (int fo = 0; fo < 4; ++fo) accO[fo] = (f32x4){0.f, 0.f, 0.f, 0.f};

#pragma unroll
        for (int s = 0; s < 4; ++s) {
            uint lx = abx[s * 2], ly = aby[s * 2];
            uint hx = abx[s * 2 + 1], hy = aby[s * 2 + 1];
            // CONVERGENT shuffles: all lanes execute every shfl, select after.
            uint l0 = (uint)__shfl((int)lx, sbase);
            uint h0 = (uint)__shfl((int)hx, sbase);
            uint l1 = (uint)__shfl((int)ly, sbase);
            uint h1 = (uint)__shfl((int)hy, sbase);
            uint l2 = (uint)__shfl((int)lx, sbase + 16);
            uint h2_ = (uint)__shfl((int)hx, sbase + 16);
            uint l3 = (uint)__shfl((int)ly, sbase + 16);
            uint h3 = (uint)__shfl((int)hy, sbase + 16);
            uint q0 = top ? h0 : l0;
            uint q1 = top ? h1 : l1;
            uint q2 = top ? h2_ : l2;
            uint q3 = top ? h3 : l3;
            union { uint4 u; bf16x8 b; } cvt;
            cvt.u = make_uint4(q0, q1, q2, q3);
#pragma unroll
            for (int fo = 0; fo < 4; ++fo) {
                bf16x8 wsA = *reinterpret_cast<const bf16x8*>(
                    smem + 65536 + ((fo * 4 + s) * 64 + lane) * 16);
                accO[fo] = __builtin_amdgcn_mfma_f32_16x16x32_bf16(wsA, cvt.b, accO[fo], 0, 0, 0);
            }
        }
#pragma unroll
        for (int fo = 0; fo < 4; ++fo)
            *reinterpret_cast<f32x4*>(OutS + (size_t)node * DS + fo * 16 + kg * 4) = accO[fo];
    }
}

extern "C" void kernel_launch(void* const* d_in, const int* in_sizes, int n_in,
                              void* d_out, int out_size, void* d_ws, size_t ws_size,
                              hipStream_t stream) {
    const float* x   = (const float*)d_in[0];
    const int*   ei  = (const int*)d_in[1];
    const float* Wl1 = (const float*)d_in[2];
    const float* bl1 = (const float*)d_in[3];
    const float* Wr1 = (const float*)d_in[4];
    const float* Wl2 = (const float*)d_in[5];
    const float* bl2 = (const float*)d_in[6];
    const float* Wr2 = (const float*)d_in[7];
    const float* Ws  = (const float*)d_in[8];

    const int* src = ei;              // edge_index[0]
    const int* dst = ei + E_EDGES;    // edge_index[1]

    char* wsb = (char*)d_ws;
    size_t off = 0;
    auto alloc = [&](size_t bytes) -> void* {
        void* p = wsb + off;
        off = (off + bytes + 255) & ~(size_t)255;
        return p;
    };
    int*    cursor = (int*)alloc(4 * (size_t)N_NODES * CPAD);
    int*    bincnt = (int*)alloc(4 * (size_t)NPART * 16);
    uint*   binned = (uint*)alloc(4 * (size_t)NPART * BCAP);
    ushort* esrc   = (ushort*)alloc(2 * (size_t)N_NODES * BUCKET);
    ushort* xb     = (ushort*)alloc(2 * (size_t)N_NODES * D);
    ushort* meanb  = (ushort*)alloc(2 * (size_t)N_NODES * D);
    ushort* h1b    = (ushort*)alloc(2 * (size_t)N_NODES * D);
    ushort* WT1f   = (ushort*)alloc(2 * 128 * 256);
    ushort* WT2f   = (ushort*)alloc(2 * 128 * 256);
    ushort* WsTf   = (ushort*)alloc(2 * 64 * 128);

    float* out_s = (float*)d_out;
    float* h2    = (float*)d_out + (size_t)N_NODES * DS;

    // prep (zero cursor/bincnt + x->bf16 + weight transposes)
    prep_kernel<<<2048, 256, 0, stream>>>(x, Wl1, Wr1, Wl2, Wr2, Ws,
                                          cursor, bincnt, xb, WT1f, WT2f, WsTf);

    // two-pass CSR build: coalesced binning, then L2-resident per-partition scatter
    bin_pass<<<1024, 256, 0, stream>>>(src, dst, bincnt, binned, E_EDGES);
    scatter_pass<<<512, 256, 0, stream>>>(binned, bincnt, cursor, esrc);

    const int GB = (NTILES + 7) / 8;  // 391 blocks, one 16-row tile per wave

    // layer 1
    aggregate_mean_bf16<<<(N_NODES + 3) / 4, 256, 0, stream>>>(xb, cursor, esrc, meanb, N_NODES);
    sage_mfma<true, false, true, false><<<GB, 512, 0, stream>>>(
        meanb, xb, WT1f, bl1, nullptr, h1b, nullptr, nullptr);

    // layer 2 (+ fused out_s)
    aggregate_mean_bf16<<<(N_NODES + 3) / 4, 256, 0, stream>>>(h1b, cursor, esrc, meanb, N_NODES);
    sage_mfma<false, true, false, true><<<GB, 512, 0, stream>>>(
        meanb, h1b, WT2f, bl2, h2, nullptr, WsTf, out_s);
}

// Round 17
// 133.375 us; speedup vs baseline: 3.2879x; 3.2879x over previous
//
#include <hip/hip_runtime.h>

#define N_NODES 50000
#define E_EDGES 640000
#define D 128
#define DS 64
#define NTILES 3125   // 50000 / 16 exactly
#define BUCKET 64     // max degree capacity (Poisson(12.8): P(>64) ~ 0)
#define CPAD 16       // one cursor counter per 64B line
#define NPART 8       // dst-range partitions (~XCDs)
#define PSIZE 6250    // N_NODES / NPART
#define BIN_BLOCKS 256
#define EPB (E_EDGES / BIN_BLOCKS)   // 2500 edges per bin block
#define LCAP 512      // per-partition LDS bin capacity (mean 312, sigma~16)

typedef __bf16 bf16x8 __attribute__((ext_vector_type(8)));
typedef float f32x4 __attribute__((ext_vector_type(4)));

static __device__ __forceinline__ ushort f2bf(float f) {
    uint u = __float_as_uint(f);
    uint r = u + 0x7fffu + ((u >> 16) & 1u);
    return (ushort)(r >> 16);
}

// ---------------- prep: zero cursor + x->bf16 + weight transposes ----------------
// Fragment-major weight layouts.
// WTf: fragment (f=n/16, s=k/32): F=f*8+s; lane l=(n&15)|(((k>>3)&3)<<4);
//      (n,k) -> WTf[(F*64+l)*8+(k&7)].  WsTf: F=(m>>4)*4+(k>>5), same inner.

__global__ void prep_kernel(const float* __restrict__ x,
                            const float* __restrict__ Wl1, const float* __restrict__ Wr1,
                            const float* __restrict__ Wl2, const float* __restrict__ Wr2,
                            const float* __restrict__ Ws,
                            int* __restrict__ cursor, ushort* __restrict__ xb,
                            ushort* __restrict__ WT1f, ushort* __restrict__ WT2f,
                            ushort* __restrict__ WsTf) {
    int tid = blockIdx.x * blockDim.x + threadIdx.x;
    int stride = gridDim.x * blockDim.x;
    for (int i = tid; i < N_NODES * CPAD; i += stride) cursor[i] = 0;
    if (tid < 32768) {
        int n = tid >> 8, k = tid & 255;
        float v = (k < 128) ? Wl1[k * 128 + n] : Wr1[(k - 128) * 128 + n];
        int F = (n >> 4) * 8 + (k >> 5);
        int l = (n & 15) | (((k >> 3) & 3) << 4);
        WT1f[(F * 64 + l) * 8 + (k & 7)] = f2bf(v);
    } else if (tid < 65536) {
        int j = tid - 32768;
        int n = j >> 8, k = j & 255;
        float v = (k < 128) ? Wl2[k * 128 + n] : Wr2[(k - 128) * 128 + n];
        int F = (n >> 4) * 8 + (k >> 5);
        int l = (n & 15) | (((k >> 3) & 3) << 4);
        WT2f[(F * 64 + l) * 8 + (k & 7)] = f2bf(v);
    } else if (tid < 73728) {
        int j = tid - 65536;
        int m = j >> 7, k = j & 127;
        int F = (m >> 4) * 4 + (k >> 5);
        int l = (m & 15) | (((k >> 3) & 3) << 4);
        WsTf[(F * 64 + l) * 8 + (k & 7)] = f2bf(Ws[k * 64 + m]);
    }
    const int n4 = N_NODES * D / 4;
    for (int i = tid; i < n4; i += stride) {
        float4 v = ((const float4*)x)[i];
        ushort4 o;
        o.x = f2bf(v.x); o.y = f2bf(v.y); o.z = f2bf(v.z); o.w = f2bf(v.w);
        ((ushort4*)xb)[i] = o;
    }
}

// ---------------- pass 1: LDS-staged dst-partition binning (ZERO global atomics) ----------------
// Each block owns a 2500-edge slice; buckets into 8 private LDS buffers (LDS
// atomics on 8 addresses only), then flushes coalescedly to its private global
// region binned[p][block][.] and writes bincnt[p][block]. Writes once, coalesced.

__global__ __launch_bounds__(256) void bin_pass(const int* __restrict__ src,
                                                const int* __restrict__ dst,
                                                int* __restrict__ bincnt,
                                                uint* __restrict__ binned) {
    __shared__ uint lbuf[NPART][LCAP];
    __shared__ int lcnt[NPART];
    if (threadIdx.x < NPART) lcnt[threadIdx.x] = 0;
    __syncthreads();
    int base = blockIdx.x * EPB;
    for (int i = threadIdx.x; i < EPB; i += blockDim.x) {
        int d = dst[base + i];
        int s = src[base + i];
        int p = d / PSIZE;
        int pos = atomicAdd(&lcnt[p], 1);
        if (pos < LCAP) lbuf[p][pos] = ((uint)d << 16) | (uint)s;
    }
    __syncthreads();
    for (int p = 0; p < NPART; ++p) {
        int n = lcnt[p]; if (n > LCAP) n = LCAP;
        uint* out = binned + ((size_t)p * BIN_BLOCKS + blockIdx.x) * LCAP;
        for (int i = threadIdx.x; i < n; i += blockDim.x) out[i] = lbuf[p][i];
        if (threadIdx.x == 0) bincnt[p * BIN_BLOCKS + blockIdx.x] = n;
    }
}

// ---------------- pass 2: per-partition scatter (L2-resident working set) ----------------
// Group g = blockIdx&7 (round-robin ~XCD) reads ONLY its partition's sub-bins;
// working set (esrc 800KB + cursor 400KB + stream ~320KB) fits one L2 ->
// bucket lines write back once.

__global__ void scatter_pass(const uint* __restrict__ binned, const int* __restrict__ bincnt,
                             int* __restrict__ cursor, ushort* __restrict__ esrc) {
    int g = blockIdx.x & (NPART - 1);
    int bchunk = blockIdx.x >> 3;
    int nb = gridDim.x >> 3;
    for (int b = bchunk; b < BIN_BLOCKS; b += nb) {
        int n = bincnt[g * BIN_BLOCKS + b];
        const uint* bin = binned + ((size_t)g * BIN_BLOCKS + b) * LCAP;
        for (int i = threadIdx.x; i < n; i += blockDim.x) {
            uint e = bin[i];
            int d = (int)(e >> 16);
            int s = (int)(e & 0xffffu);
            int pos = atomicAdd(&cursor[d * CPAD], 1);
            if (pos < BUCKET) esrc[d * BUCKET + pos] = (ushort)s;
        }
    }
}

// ---------------- segment mean, bf16 in/out ----------------
// one wave per dst node (50k waves -> max gather TLP); 16 lanes x 16B cover a
// 256B row; 16 edges in flight per iter

__global__ void aggregate_mean_bf16(const ushort* __restrict__ feat, const int* __restrict__ cursor,
                                    const ushort* __restrict__ esrc, ushort* __restrict__ mean, int n) {
    int wid = threadIdx.x >> 6;           // 4 waves per block
    int lane = threadIdx.x & 63;
    int d = blockIdx.x * 4 + wid;
    if (d >= n) return;
    int cnt = cursor[d * CPAD]; if (cnt > BUCKET) cnt = BUCKET;
    int beg = d * BUCKET;
    int g = lane >> 4;                    // edge group 0..3
    int gl = lane & 15;                   // 16B chunk within row

    float acc[8] = {0.f, 0.f, 0.f, 0.f, 0.f, 0.f, 0.f, 0.f};
    for (int i = 0; i < cnt; i += 16) {
        uint4 v[4];
#pragma unroll
        for (int j = 0; j < 4; ++j) {
            int idx = i + g + j * 4;
            v[j] = make_uint4(0u, 0u, 0u, 0u);
            if (idx < cnt) {
                int e = esrc[beg + idx];
                v[j] = ((const uint4*)(feat + (size_t)e * D))[gl];
            }
        }
#pragma unroll
        for (int j = 0; j < 4; ++j) {
            acc[0] += __uint_as_float(v[j].x << 16);
            acc[1] += __uint_as_float(v[j].x & 0xffff0000u);
            acc[2] += __uint_as_float(v[j].y << 16);
            acc[3] += __uint_as_float(v[j].y & 0xffff0000u);
            acc[4] += __uint_as_float(v[j].z << 16);
            acc[5] += __uint_as_float(v[j].z & 0xffff0000u);
            acc[6] += __uint_as_float(v[j].w << 16);
            acc[7] += __uint_as_float(v[j].w & 0xffff0000u);
        }
    }
#pragma unroll
    for (int m = 16; m <= 32; m <<= 1) {
#pragma unroll
        for (int j = 0; j < 8; ++j) acc[j] += __shfl_xor(acc[j], m);
    }
    if (g == 0) {
        float inv = (cnt > 0) ? 1.0f / (float)cnt : 0.0f;
        uint4 o;
        o.x = (uint)f2bf(acc[0] * inv) | ((uint)f2bf(acc[1] * inv) << 16);
        o.y = (uint)f2bf(acc[2] * inv) | ((uint)f2bf(acc[3] * inv) << 16);
        o.z = (uint)f2bf(acc[4] * inv) | ((uint)f2bf(acc[5] * inv) << 16);
        o.w = (uint)f2bf(acc[6] * inv) | ((uint)f2bf(acc[7] * inv) << 16);
        ((uint4*)(mean + (size_t)d * D))[gl] = o;
    }
}

// ---------------- fused SAGE MFMA GEMM: C = [mean|self] @ WT^T + b ----------------
// ONE 16-row tile per wave (no loop, no prefetch -> no spill).
// Swapped operands: mfma(W_frag, Act_frag) -> lane&15 = node, quad = feature.
// Lane's f32x4 acc is feature-contiguous -> 16B f32 / 8B bf16 stores.
// OUTS: fuse out_s = h2 @ Ws via convergent-shfl redistribution + Ws frags in LDS.

template <bool RELU, bool WF32, bool WBF16, bool OUTS>
__global__ __launch_bounds__(512) void sage_mfma(
    const ushort* __restrict__ A1, const ushort* __restrict__ A2,
    const ushort* __restrict__ WTf, const float* __restrict__ bias,
    float* __restrict__ Hf, ushort* __restrict__ Hb,
    const ushort* __restrict__ WsTf, float* __restrict__ OutS)
{
    __shared__ __attribute__((aligned(16))) char smem[OUTS ? 81920 : 65536];
    int w = threadIdx.x >> 6, lane = threadIdx.x & 63;

    // stage WTf linearly (64 KB, fragment-major; dest = uniform base + lane*16)
#pragma unroll
    for (int it = 0; it < 8; ++it) {
        int off = w * 8192 + it * 1024;
        __builtin_amdgcn_global_load_lds(
            (const __attribute__((address_space(1))) void*)((const char*)WTf + off + lane * 16),
            (__attribute__((address_space(3))) void*)(smem + off), 16, 0, 0);
    }
    if (OUTS) {   // stage WsTf (16 KB) at smem+65536
#pragma unroll
        for (int it = 0; it < 2; ++it) {
            int off = w * 2048 + it * 1024;
            __builtin_amdgcn_global_load_lds(
                (const __attribute__((address_space(1))) void*)((const char*)WsTf + off + lane * 16),
                (__attribute__((address_space(3))) void*)(smem + 65536 + off), 16, 0, 0);
        }
    }

    int rl = lane & 15;       // node within tile
    int kg = lane >> 4;       // k-subgroup / feature quad
    int tile = blockIdx.x * 8 + w;

    bf16x8 a[8];
    if (tile < NTILES) {
        const ushort* r1 = A1 + (size_t)(tile * 16 + rl) * 128 + kg * 8;
        const ushort* r2 = A2 + (size_t)(tile * 16 + rl) * 128 + kg * 8;
#pragma unroll
        for (int s = 0; s < 4; ++s) a[s] = *reinterpret_cast<const bf16x8*>(r1 + s * 32);
#pragma unroll
        for (int s = 0; s < 4; ++s) a[4 + s] = *reinterpret_cast<const bf16x8*>(r2 + s * 32);
    }
    __syncthreads();          // staging visible to all waves
    if (tile >= NTILES) return;

    // acc init = bias (broadcast over nodes; lane's features f*16+kg*4..+3)
    f32x4 acc[8];
#pragma unroll
    for (int f = 0; f < 8; ++f)
        acc[f] = *reinterpret_cast<const f32x4*>(bias + f * 16 + kg * 4);

#pragma unroll
    for (int s = 0; s < 8; ++s) {
#pragma unroll
        for (int f = 0; f < 8; ++f) {
            bf16x8 b = *reinterpret_cast<const bf16x8*>(smem + ((f * 8 + s) * 64 + lane) * 16);
            acc[f] = __builtin_amdgcn_mfma_f32_16x16x32_bf16(b, a[s], acc[f], 0, 0, 0);
        }
    }

    int node = tile * 16 + rl;
    // epilogue: lane holds features n = f*16 + kg*4 + (0..3) of `node`
#pragma unroll
    for (int f = 0; f < 8; ++f) {
        f32x4 v = acc[f];
        if (RELU) {
            v[0] = fmaxf(v[0], 0.f); v[1] = fmaxf(v[1], 0.f);
            v[2] = fmaxf(v[2], 0.f); v[3] = fmaxf(v[3], 0.f);
        }
        acc[f] = v;
        size_t o = (size_t)node * 128 + f * 16 + kg * 4;
        if (WF32)
            *reinterpret_cast<f32x4*>(Hf + o) = v;
        if (WBF16) {
            ushort4 ob;
            ob.x = f2bf(v[0]); ob.y = f2bf(v[1]); ob.z = f2bf(v[2]); ob.w = f2bf(v[3]);
            *reinterpret_cast<ushort4*>(Hb + o) = ob;
        }
    }

    if (OUTS) {
        // lane holds bf16(h2) features f*16+kg*4..+3 packed: abx=(e0,e1), aby=(e2,e3)
        uint abx[8], aby[8];
#pragma unroll
        for (int f = 0; f < 8; ++f) {
            abx[f] = (uint)f2bf(acc[f][0]) | ((uint)f2bf(acc[f][1]) << 16);
            aby[f] = (uint)f2bf(acc[f][2]) | ((uint)f2bf(acc[f][3]) << 16);
        }
        int sbase = rl + ((lane & 16) << 1);   // rl + (kg&1)*32
        bool top = lane >= 32;                 // kg>>1
        f32x4 accO[4];
#pragma unroll
        for (int fo = 0; fo < 4; ++fo) accO[fo] = (f32x4){0.f, 0.f, 0.f, 0.f};

#pragma unroll
        for (int s = 0; s < 4; ++s) {
            uint lx = abx[s * 2], ly = aby[s * 2];
            uint hx = abx[s * 2 + 1], hy = aby[s * 2 + 1];
            // CONVERGENT shuffles: all lanes execute every shfl, select after.
            uint l0 = (uint)__shfl((int)lx, sbase);
            uint h0 = (uint)__shfl((int)hx, sbase);
            uint l1 = (uint)__shfl((int)ly, sbase);
            uint h1 = (uint)__shfl((int)hy, sbase);
            uint l2 = (uint)__shfl((int)lx, sbase + 16);
            uint h2_ = (uint)__shfl((int)hx, sbase + 16);
            uint l3 = (uint)__shfl((int)ly, sbase + 16);
            uint h3 = (uint)__shfl((int)hy, sbase + 16);
            uint q0 = top ? h0 : l0;
            uint q1 = top ? h1 : l1;
            uint q2 = top ? h2_ : l2;
            uint q3 = top ? h3 : l3;
            union { uint4 u; bf16x8 b; } cvt;
            cvt.u = make_uint4(q0, q1, q2, q3);
#pragma unroll
            for (int fo = 0; fo < 4; ++fo) {
                bf16x8 wsA = *reinterpret_cast<const bf16x8*>(
                    smem + 65536 + ((fo * 4 + s) * 64 + lane) * 16);
                accO[fo] = __builtin_amdgcn_mfma_f32_16x16x32_bf16(wsA, cvt.b, accO[fo], 0, 0, 0);
            }
        }
#pragma unroll
        for (int fo = 0; fo < 4; ++fo)
            *reinterpret_cast<f32x4*>(OutS + (size_t)node * DS + fo * 16 + kg * 4) = accO[fo];
    }
}

extern "C" void kernel_launch(void* const* d_in, const int* in_sizes, int n_in,
                              void* d_out, int out_size, void* d_ws, size_t ws_size,
                              hipStream_t stream) {
    const float* x   = (const float*)d_in[0];
    const int*   ei  = (const int*)d_in[1];
    const float* Wl1 = (const float*)d_in[2];
    const float* bl1 = (const float*)d_in[3];
    const float* Wr1 = (const float*)d_in[4];
    const float* Wl2 = (const float*)d_in[5];
    const float* bl2 = (const float*)d_in[6];
    const float* Wr2 = (const float*)d_in[7];
    const float* Ws  = (const float*)d_in[8];

    const int* src = ei;              // edge_index[0]
    const int* dst = ei + E_EDGES;    // edge_index[1]

    char* wsb = (char*)d_ws;
    size_t off = 0;
    auto alloc = [&](size_t bytes) -> void* {
        void* p = wsb + off;
        off = (off + bytes + 255) & ~(size_t)255;
        return p;
    };
    int*    cursor = (int*)alloc(4 * (size_t)N_NODES * CPAD);
    int*    bincnt = (int*)alloc(4 * (size_t)NPART * BIN_BLOCKS);
    uint*   binned = (uint*)alloc(4 * (size_t)NPART * BIN_BLOCKS * LCAP);
    ushort* esrc   = (ushort*)alloc(2 * (size_t)N_NODES * BUCKET);
    ushort* xb     = (ushort*)alloc(2 * (size_t)N_NODES * D);
    ushort* meanb  = (ushort*)alloc(2 * (size_t)N_NODES * D);
    ushort* h1b    = (ushort*)alloc(2 * (size_t)N_NODES * D);
    ushort* WT1f   = (ushort*)alloc(2 * 128 * 256);
    ushort* WT2f   = (ushort*)alloc(2 * 128 * 256);
    ushort* WsTf   = (ushort*)alloc(2 * 64 * 128);

    float* out_s = (float*)d_out;
    float* h2    = (float*)d_out + (size_t)N_NODES * DS;

    // prep (zero cursor + x->bf16 + weight transposes)
    prep_kernel<<<2048, 256, 0, stream>>>(x, Wl1, Wr1, Wl2, Wr2, Ws,
                                          cursor, xb, WT1f, WT2f, WsTf);

    // two-pass CSR build: LDS-staged coalesced binning (no global atomics),
    // then L2-resident per-partition scatter
    bin_pass<<<BIN_BLOCKS, 256, 0, stream>>>(src, dst, bincnt, binned);
    scatter_pass<<<512, 256, 0, stream>>>(binned, bincnt, cursor, esrc);

    const int GB = (NTILES + 7) / 8;  // 391 blocks, one 16-row tile per wave

    // layer 1
    aggregate_mean_bf16<<<(N_NODES + 3) / 4, 256, 0, stream>>>(xb, cursor, esrc, meanb, N_NODES);
    sage_mfma<true, false, true, false><<<GB, 512, 0, stream>>>(
        meanb, xb, WT1f, bl1, nullptr, h1b, nullptr, nullptr);

    // layer 2 (+ fused out_s)
    aggregate_mean_bf16<<<(N_NODES + 3) / 4, 256, 0, stream>>>(h1b, cursor, esrc, meanb, N_NODES);
    sage_mfma<false, true, false, true><<<GB, 512, 0, stream>>>(
        meanb, h1b, WT2f, bl2, h2, nullptr, WsTf, out_s);
}

// Round 18
// 126.804 us; speedup vs baseline: 3.4583x; 1.0518x over previous
//
#include <hip/hip_runtime.h>

#define N_NODES 50000
#define E_EDGES 640000
#define D 128
#define DS 64
#define NTILES 3125   // 50000 / 16 exactly
#define BUCKET 64     // max degree capacity (Poisson(12.8): P(>64) ~ 0)
#define CPAD 16       // one cursor counter per 64B line
#define NPART 8       // dst-range partitions (~XCDs)
#define PSIZE 6250    // N_NODES / NPART

typedef __bf16 bf16x8 __attribute__((ext_vector_type(8)));
typedef float f32x4 __attribute__((ext_vector_type(4)));

static __device__ __forceinline__ ushort f2bf(float f) {
    uint u = __float_as_uint(f);
    uint r = u + 0x7fffu + ((u >> 16) & 1u);
    return (ushort)(r >> 16);
}

// ---------------- fused prep: zero cursor + x->bf16 + weight transposes ----------------
// Fragment-major weight layouts.
// WTf: fragment (f=n/16, s=k/32): F=f*8+s; lane l=(n&15)|(((k>>3)&3)<<4);
//      (n,k) -> WTf[(F*64+l)*8+(k&7)].  WsTf: F=(m>>4)*4+(k>>5), same inner.

__global__ void prep_kernel(const float* __restrict__ x,
                            const float* __restrict__ Wl1, const float* __restrict__ Wr1,
                            const float* __restrict__ Wl2, const float* __restrict__ Wr2,
                            const float* __restrict__ Ws,
                            int* __restrict__ cursor, ushort* __restrict__ xb,
                            ushort* __restrict__ WT1f, ushort* __restrict__ WT2f,
                            ushort* __restrict__ WsTf) {
    int tid = blockIdx.x * blockDim.x + threadIdx.x;
    int stride = gridDim.x * blockDim.x;
    for (int i = tid; i < N_NODES * CPAD; i += stride) cursor[i] = 0;
    if (tid < 32768) {
        int n = tid >> 8, k = tid & 255;
        float v = (k < 128) ? Wl1[k * 128 + n] : Wr1[(k - 128) * 128 + n];
        int F = (n >> 4) * 8 + (k >> 5);
        int l = (n & 15) | (((k >> 3) & 3) << 4);
        WT1f[(F * 64 + l) * 8 + (k & 7)] = f2bf(v);
    } else if (tid < 65536) {
        int j = tid - 32768;
        int n = j >> 8, k = j & 255;
        float v = (k < 128) ? Wl2[k * 128 + n] : Wr2[(k - 128) * 128 + n];
        int F = (n >> 4) * 8 + (k >> 5);
        int l = (n & 15) | (((k >> 3) & 3) << 4);
        WT2f[(F * 64 + l) * 8 + (k & 7)] = f2bf(v);
    } else if (tid < 73728) {
        int j = tid - 65536;
        int m = j >> 7, k = j & 127;
        int F = (m >> 4) * 4 + (k >> 5);
        int l = (m & 15) | (((k >> 3) & 3) << 4);
        WsTf[(F * 64 + l) * 8 + (k & 7)] = f2bf(Ws[k * 64 + m]);
    }
    const int n4 = N_NODES * D / 4;
    for (int i = tid; i < n4; i += stride) {
        float4 v = ((const float4*)x)[i];
        ushort4 o;
        o.x = f2bf(v.x); o.y = f2bf(v.y); o.z = f2bf(v.z); o.w = f2bf(v.w);
        ((ushort4*)xb)[i] = o;
    }
}

// ---------------- partitioned single-pass bucket fill ----------------
// Group g = blockIdx&7 handles dst range [g*PSIZE,(g+1)*PSIZE). esrc scatter
// stores are NON-TEMPORAL (write-through, no L2 dirty-line residency): each
// 2B store costs one <=32B burst instead of a deferred 64B line writeback
// churned across 8 non-coherent XCD L2s.

__global__ void fill_part(const int* __restrict__ src, const int* __restrict__ dst,
                          int* __restrict__ cursor, ushort* __restrict__ esrc, int e) {
    int g = blockIdx.x & (NPART - 1);     // partition / ~XCD (round-robin heuristic)
    int bchunk = blockIdx.x >> 3;         // block within group
    int lo = g * PSIZE, hi = lo + PSIZE;
    int nb = gridDim.x >> 3;
    int i = bchunk * blockDim.x + threadIdx.x;
    int stride = nb * blockDim.x;
    for (; i < e; i += stride) {
        int d = dst[i];
        if (d >= lo && d < hi) {
            int pos = atomicAdd(&cursor[d * CPAD], 1);
            if (pos < BUCKET)
                __builtin_nontemporal_store((ushort)src[i], &esrc[d * BUCKET + pos]);
        }
    }
}

// ---------------- segment mean, bf16 in/out ----------------
// one wave per dst node (50k waves -> max gather TLP); 16 lanes x 16B cover a
// 256B row; 16 edges in flight per iter

__global__ void aggregate_mean_bf16(const ushort* __restrict__ feat, const int* __restrict__ cursor,
                                    const ushort* __restrict__ esrc, ushort* __restrict__ mean, int n) {
    int wid = threadIdx.x >> 6;           // 4 waves per block
    int lane = threadIdx.x & 63;
    int d = blockIdx.x * 4 + wid;
    if (d >= n) return;
    int cnt = cursor[d * CPAD]; if (cnt > BUCKET) cnt = BUCKET;
    int beg = d * BUCKET;
    int g = lane >> 4;                    // edge group 0..3
    int gl = lane & 15;                   // 16B chunk within row

    float acc[8] = {0.f, 0.f, 0.f, 0.f, 0.f, 0.f, 0.f, 0.f};
    for (int i = 0; i < cnt; i += 16) {
        uint4 v[4];
#pragma unroll
        for (int j = 0; j < 4; ++j) {
            int idx = i + g + j * 4;
            v[j] = make_uint4(0u, 0u, 0u, 0u);
            if (idx < cnt) {
                int e = esrc[beg + idx];
                v[j] = ((const uint4*)(feat + (size_t)e * D))[gl];
            }
        }
#pragma unroll
        for (int j = 0; j < 4; ++j) {
            acc[0] += __uint_as_float(v[j].x << 16);
            acc[1] += __uint_as_float(v[j].x & 0xffff0000u);
            acc[2] += __uint_as_float(v[j].y << 16);
            acc[3] += __uint_as_float(v[j].y & 0xffff0000u);
            acc[4] += __uint_as_float(v[j].z << 16);
            acc[5] += __uint_as_float(v[j].z & 0xffff0000u);
            acc[6] += __uint_as_float(v[j].w << 16);
            acc[7] += __uint_as_float(v[j].w & 0xffff0000u);
        }
    }
#pragma unroll
    for (int m = 16; m <= 32; m <<= 1) {
#pragma unroll
        for (int j = 0; j < 8; ++j) acc[j] += __shfl_xor(acc[j], m);
    }
    if (g == 0) {
        float inv = (cnt > 0) ? 1.0f / (float)cnt : 0.0f;
        uint4 o;
        o.x = (uint)f2bf(acc[0] * inv) | ((uint)f2bf(acc[1] * inv) << 16);
        o.y = (uint)f2bf(acc[2] * inv) | ((uint)f2bf(acc[3] * inv) << 16);
        o.z = (uint)f2bf(acc[4] * inv) | ((uint)f2bf(acc[5] * inv) << 16);
        o.w = (uint)f2bf(acc[6] * inv) | ((uint)f2bf(acc[7] * inv) << 16);
        ((uint4*)(mean + (size_t)d * D))[gl] = o;
    }
}

// ---------------- fused SAGE MFMA GEMM: C = [mean|self] @ WT^T + b ----------------
// ONE 16-row tile per wave (no loop, no prefetch -> no spill).
// Swapped operands: mfma(W_frag, Act_frag) -> lane&15 = node, quad = feature.
// Lane's f32x4 acc is feature-contiguous -> 16B f32 / 8B bf16 stores.
// OUTS: fuse out_s = h2 @ Ws via convergent-shfl redistribution + Ws frags in LDS.

template <bool RELU, bool WF32, bool WBF16, bool OUTS>
__global__ __launch_bounds__(512) void sage_mfma(
    const ushort* __restrict__ A1, const ushort* __restrict__ A2,
    const ushort* __restrict__ WTf, const float* __restrict__ bias,
    float* __restrict__ Hf, ushort* __restrict__ Hb,
    const ushort* __restrict__ WsTf, float* __restrict__ OutS)
{
    __shared__ __attribute__((aligned(16))) char smem[OUTS ? 81920 : 65536];
    int w = threadIdx.x >> 6, lane = threadIdx.x & 63;

    // stage WTf linearly (64 KB, fragment-major; dest = uniform base + lane*16)
#pragma unroll
    for (int it = 0; it < 8; ++it) {
        int off = w * 8192 + it * 1024;
        __builtin_amdgcn_global_load_lds(
            (const __attribute__((address_space(1))) void*)((const char*)WTf + off + lane * 16),
            (__attribute__((address_space(3))) void*)(smem + off), 16, 0, 0);
    }
    if (OUTS) {   // stage WsTf (16 KB) at smem+65536
#pragma unroll
        for (int it = 0; it < 2; ++it) {
            int off = w * 2048 + it * 1024;
            __builtin_amdgcn_global_load_lds(
                (const __attribute__((address_space(1))) void*)((const char*)WsTf + off + lane * 16),
                (__attribute__((address_space(3))) void*)(smem + 65536 + off), 16, 0, 0);
        }
    }

    int rl = lane & 15;       // node within tile
    int kg = lane >> 4;       // k-subgroup / feature quad
    int tile = blockIdx.x * 8 + w;

    bf16x8 a[8];
    if (tile < NTILES) {
        const ushort* r1 = A1 + (size_t)(tile * 16 + rl) * 128 + kg * 8;
        const ushort* r2 = A2 + (size_t)(tile * 16 + rl) * 128 + kg * 8;
#pragma unroll
        for (int s = 0; s < 4; ++s) a[s] = *reinterpret_cast<const bf16x8*>(r1 + s * 32);
#pragma unroll
        for (int s = 0; s < 4; ++s) a[4 + s] = *reinterpret_cast<const bf16x8*>(r2 + s * 32);
    }
    __syncthreads();          // staging visible to all waves
    if (tile >= NTILES) return;

    // acc init = bias (broadcast over nodes; lane's features f*16+kg*4..+3)
    f32x4 acc[8];
#pragma unroll
    for (int f = 0; f < 8; ++f)
        acc[f] = *reinterpret_cast<const f32x4*>(bias + f * 16 + kg * 4);

#pragma unroll
    for (int s = 0; s < 8; ++s) {
#pragma unroll
        for (int f = 0; f < 8; ++f) {
            bf16x8 b = *reinterpret_cast<const bf16x8*>(smem + ((f * 8 + s) * 64 + lane) * 16);
            acc[f] = __builtin_amdgcn_mfma_f32_16x16x32_bf16(b, a[s], acc[f], 0, 0, 0);
        }
    }

    int node = tile * 16 + rl;
    // epilogue: lane holds features n = f*16 + kg*4 + (0..3) of `node`
#pragma unroll
    for (int f = 0; f < 8; ++f) {
        f32x4 v = acc[f];
        if (RELU) {
            v[0] = fmaxf(v[0], 0.f); v[1] = fmaxf(v[1], 0.f);
            v[2] = fmaxf(v[2], 0.f); v[3] = fmaxf(v[3], 0.f);
        }
        acc[f] = v;
        size_t o = (size_t)node * 128 + f * 16 + kg * 4;
        if (WF32)
            *reinterpret_cast<f32x4*>(Hf + o) = v;
        if (WBF16) {
            ushort4 ob;
            ob.x = f2bf(v[0]); ob.y = f2bf(v[1]); ob.z = f2bf(v[2]); ob.w = f2bf(v[3]);
            *reinterpret_cast<ushort4*>(Hb + o) = ob;
        }
    }

    if (OUTS) {
        // lane holds bf16(h2) features f*16+kg*4..+3 packed: abx=(e0,e1), aby=(e2,e3)
        uint abx[8], aby[8];
#pragma unroll
        for (int f = 0; f < 8; ++f) {
            abx[f] = (uint)f2bf(acc[f][0]) | ((uint)f2bf(acc[f][1]) << 16);
            aby[f] = (uint)f2bf(acc[f][2]) | ((uint)f2bf(acc[f][3]) << 16);
        }
        int sbase = rl + ((lane & 16) << 1);   // rl + (kg&1)*32
        bool top = lane >= 32;                 // kg>>1
        f32x4 accO[4];
#pragma unroll
        for (int fo = 0; fo < 4; ++fo) accO[fo] = (f32x4){0.f, 0.f, 0.f, 0.f};

#pragma unroll
        for (int s = 0; s < 4; ++s) {
            uint lx = abx[s * 2], ly = aby[s * 2];
            uint hx = abx[s * 2 + 1], hy = aby[s * 2 + 1];
            // CONVERGENT shuffles: all lanes execute every shfl, select after.
            uint l0 = (uint)__shfl((int)lx, sbase);
            uint h0 = (uint)__shfl((int)hx, sbase);
            uint l1 = (uint)__shfl((int)ly, sbase);
            uint h1 = (uint)__shfl((int)hy, sbase);
            uint l2 = (uint)__shfl((int)lx, sbase + 16);
            uint h2_ = (uint)__shfl((int)hx, sbase + 16);
            uint l3 = (uint)__shfl((int)ly, sbase + 16);
            uint h3 = (uint)__shfl((int)hy, sbase + 16);
            uint q0 = top ? h0 : l0;
            uint q1 = top ? h1 : l1;
            uint q2 = top ? h2_ : l2;
            uint q3 = top ? h3 : l3;
            union { uint4 u; bf16x8 b; } cvt;
            cvt.u = make_uint4(q0, q1, q2, q3);
#pragma unroll
            for (int fo = 0; fo < 4; ++fo) {
                bf16x8 wsA = *reinterpret_cast<const bf16x8*>(
                    smem + 65536 + ((fo * 4 + s) * 64 + lane) * 16);
                accO[fo] = __builtin_amdgcn_mfma_f32_16x16x32_bf16(wsA, cvt.b, accO[fo], 0, 0, 0);
            }
        }
#pragma unroll
        for (int fo = 0; fo < 4; ++fo)
            *reinterpret_cast<f32x4*>(OutS + (size_t)node * DS + fo * 16 + kg * 4) = accO[fo];
    }
}

extern "C" void kernel_launch(void* const* d_in, const int* in_sizes, int n_in,
                              void* d_out, int out_size, void* d_ws, size_t ws_size,
                              hipStream_t stream) {
    const float* x   = (const float*)d_in[0];
    const int*   ei  = (const int*)d_in[1];
    const float* Wl1 = (const float*)d_in[2];
    const float* bl1 = (const float*)d_in[3];
    const float* Wr1 = (const float*)d_in[4];
    const float* Wl2 = (const float*)d_in[5];
    const float* bl2 = (const float*)d_in[6];
    const float* Wr2 = (const float*)d_in[7];
    const float* Ws  = (const float*)d_in[8];

    const int* src = ei;              // edge_index[0]
    const int* dst = ei + E_EDGES;    // edge_index[1]

    char* wsb = (char*)d_ws;
    size_t off = 0;
    auto alloc = [&](size_t bytes) -> void* {
        void* p = wsb + off;
        off = (off + bytes + 255) & ~(size_t)255;
        return p;
    };
    int*    cursor = (int*)alloc(4 * (size_t)N_NODES * CPAD);
    ushort* esrc   = (ushort*)alloc(2 * (size_t)N_NODES * BUCKET);
    ushort* xb     = (ushort*)alloc(2 * (size_t)N_NODES * D);
    ushort* meanb  = (ushort*)alloc(2 * (size_t)N_NODES * D);
    ushort* h1b    = (ushort*)alloc(2 * (size_t)N_NODES * D);
    ushort* WT1f   = (ushort*)alloc(2 * 128 * 256);
    ushort* WT2f   = (ushort*)alloc(2 * 128 * 256);
    ushort* WsTf   = (ushort*)alloc(2 * 64 * 128);

    float* out_s = (float*)d_out;
    float* h2    = (float*)d_out + (size_t)N_NODES * DS;

    // prep (zero cursor + x->bf16 + weight transposes)
    prep_kernel<<<2048, 256, 0, stream>>>(x, Wl1, Wr1, Wl2, Wr2, Ws,
                                          cursor, xb, WT1f, WT2f, WsTf);

    // partitioned single-pass bucket CSR (1024 blocks = 8 groups x 128), NT scatter stores
    fill_part<<<1024, 256, 0, stream>>>(src, dst, cursor, esrc, E_EDGES);

    const int GB = (NTILES + 7) / 8;  // 391 blocks, one 16-row tile per wave

    // layer 1
    aggregate_mean_bf16<<<(N_NODES + 3) / 4, 256, 0, stream>>>(xb, cursor, esrc, meanb, N_NODES);
    sage_mfma<true, false, true, false><<<GB, 512, 0, stream>>>(
        meanb, xb, WT1f, bl1, nullptr, h1b, nullptr, nullptr);

    // layer 2 (+ fused out_s)
    aggregate_mean_bf16<<<(N_NODES + 3) / 4, 256, 0, stream>>>(h1b, cursor, esrc, meanb, N_NODES);
    sage_mfma<false, true, false, true><<<GB, 512, 0, stream>>>(
        meanb, h1b, WT2f, bl2, h2, nullptr, WsTf, out_s);
}

// Round 19
// 126.683 us; speedup vs baseline: 3.4616x; 1.0010x over previous
//
#include <hip/hip_runtime.h>

#define N_NODES 50000
#define E_EDGES 640000
#define D 128
#define DS 64
#define NTILES 3125   // 50000 / 16 exactly
#define BUCKET 64     // max degree capacity (Poisson(12.8): P(>64) ~ 0)
#define CPAD 16       // one cursor counter per 64B line
#define NPART2 256    // dst partitions for counting sort
#define PSZ 196       // ceil(N_NODES / NPART2); 256*196 = 50176 >= 50000
#define BIN_BLOCKS 256
#define EPB 2500      // E_EDGES / BIN_BLOCKS
#define SCAP 32       // per (block,partition) sub-bin capacity (mean 9.8, sigma 3.1)
#define SORTCAP 3072  // per-partition edge capacity (mean 2509, sigma 50)

typedef __bf16 bf16x8 __attribute__((ext_vector_type(8)));
typedef float f32x4 __attribute__((ext_vector_type(4)));

static __device__ __forceinline__ ushort f2bf(float f) {
    uint u = __float_as_uint(f);
    uint r = u + 0x7fffu + ((u >> 16) & 1u);
    return (ushort)(r >> 16);
}

// ---------------- prep: x->bf16 + weight transposes (no cursor zero needed) ----------------
// Fragment-major weight layouts.
// WTf: fragment (f=n/16, s=k/32): F=f*8+s; lane l=(n&15)|(((k>>3)&3)<<4);
//      (n,k) -> WTf[(F*64+l)*8+(k&7)].  WsTf: F=(m>>4)*4+(k>>5), same inner.

__global__ void prep_kernel(const float* __restrict__ x,
                            const float* __restrict__ Wl1, const float* __restrict__ Wr1,
                            const float* __restrict__ Wl2, const float* __restrict__ Wr2,
                            const float* __restrict__ Ws,
                            ushort* __restrict__ xb,
                            ushort* __restrict__ WT1f, ushort* __restrict__ WT2f,
                            ushort* __restrict__ WsTf) {
    int tid = blockIdx.x * blockDim.x + threadIdx.x;
    int stride = gridDim.x * blockDim.x;
    if (tid < 32768) {
        int n = tid >> 8, k = tid & 255;
        float v = (k < 128) ? Wl1[k * 128 + n] : Wr1[(k - 128) * 128 + n];
        int F = (n >> 4) * 8 + (k >> 5);
        int l = (n & 15) | (((k >> 3) & 3) << 4);
        WT1f[(F * 64 + l) * 8 + (k & 7)] = f2bf(v);
    } else if (tid < 65536) {
        int j = tid - 32768;
        int n = j >> 8, k = j & 255;
        float v = (k < 128) ? Wl2[k * 128 + n] : Wr2[(k - 128) * 128 + n];
        int F = (n >> 4) * 8 + (k >> 5);
        int l = (n & 15) | (((k >> 3) & 3) << 4);
        WT2f[(F * 64 + l) * 8 + (k & 7)] = f2bf(v);
    } else if (tid < 73728) {
        int j = tid - 65536;
        int m = j >> 7, k = j & 127;
        int F = (m >> 4) * 4 + (k >> 5);
        int l = (m & 15) | (((k >> 3) & 3) << 4);
        WsTf[(F * 64 + l) * 8 + (k & 7)] = f2bf(Ws[k * 64 + m]);
    }
    const int n4 = N_NODES * D / 4;
    for (int i = tid; i < n4; i += stride) {
        float4 v = ((const float4*)x)[i];
        ushort4 o;
        o.x = f2bf(v.x); o.y = f2bf(v.y); o.z = f2bf(v.z); o.w = f2bf(v.w);
        ((ushort4*)xb)[i] = o;
    }
}

// ---------------- pass 1: LDS binning into 256 dst-partitions (zero global atomics) ----------------
// Block owns a 2500-edge slice; buckets into 256 LDS sub-bins, then flushes each
// sub-bin contiguously to binned[p][block][SCAP]. All global writes coalesced-ish.

__global__ __launch_bounds__(256) void bin_pass(const int* __restrict__ src,
                                                const int* __restrict__ dst,
                                                int* __restrict__ bincnt,
                                                uint* __restrict__ binned) {
    __shared__ uint lbuf[NPART2][SCAP];   // 32 KB
    __shared__ int lcnt[NPART2];
    for (int i = threadIdx.x; i < NPART2; i += 256) lcnt[i] = 0;
    __syncthreads();
    int base = blockIdx.x * EPB;
    for (int i = threadIdx.x; i < EPB; i += 256) {
        int d = dst[base + i];
        int s = src[base + i];
        int p = d / PSZ;
        int pos = atomicAdd(&lcnt[p], 1);
        if (pos < SCAP) lbuf[p][pos] = ((uint)d << 16) | (uint)s;
    }
    __syncthreads();
    // flush: 8 partitions x 32 slots per iteration
    int pl = threadIdx.x >> 5;
    int sl = threadIdx.x & 31;
    for (int pb = 0; pb < NPART2; pb += 8) {
        int p = pb + pl;
        int n = lcnt[p]; if (n > SCAP) n = SCAP;
        if (sl < n)
            binned[((size_t)p * BIN_BLOCKS + blockIdx.x) * SCAP + sl] = lbuf[p][sl];
        if (sl == 0) bincnt[p * BIN_BLOCKS + blockIdx.x] = n;
    }
}

// ---------------- pass 2: per-partition LDS counting sort + vectorized bucket writes ----------------
// One block per partition (196 nodes, ~2500 edges). Reads its 32KB bin region
// coalescedly, counts degrees in LDS, prefix-sums, places src into sorted LDS
// runs, then writes each node's bucket with 16B stores and its degree once.
// Replaces 1.3M random global transactions with ~350k mostly-coalesced ones.

__global__ __launch_bounds__(256) void sort_pass(const uint* __restrict__ binned,
                                                 const int* __restrict__ bincnt,
                                                 int* __restrict__ cursor,
                                                 ushort* __restrict__ esrc) {
    int p = blockIdx.x;
    int lo = p * PSZ;
    int nnodes = N_NODES - lo; if (nnodes > PSZ) nnodes = PSZ;
    if (nnodes <= 0) return;

    __shared__ int cnts[BIN_BLOCKS];      // sub-bin counts
    __shared__ int ldeg[PSZ];
    __shared__ int lstart[PSZ];
    __shared__ int lcur[PSZ];
    __shared__ int pref[256];
    __shared__ ushort sorted[SORTCAP];    // 6 KB

    for (int b = threadIdx.x; b < BIN_BLOCKS; b += 256)
        cnts[b] = bincnt[p * BIN_BLOCKS + b];
    for (int i = threadIdx.x; i < PSZ; i += 256) ldeg[i] = 0;
    __syncthreads();

    const uint* bin = binned + (size_t)p * BIN_BLOCKS * SCAP;

    // pass A: count degrees
    for (int slot = threadIdx.x; slot < BIN_BLOCKS * SCAP; slot += 256) {
        if ((slot & (SCAP - 1)) < cnts[slot / SCAP]) {
            uint e = bin[slot];
            atomicAdd(&ldeg[(int)(e >> 16) - lo], 1);
        }
    }
    __syncthreads();

    // exclusive prefix over PSZ degrees (Hillis-Steele, 256 threads)
    int t = threadIdx.x;
    pref[t] = (t < PSZ) ? ldeg[t] : 0;
    __syncthreads();
#pragma unroll
    for (int off = 1; off < 256; off <<= 1) {
        int v = (t >= off) ? pref[t - off] : 0;
        __syncthreads();
        pref[t] += v;
        __syncthreads();
    }
    if (t < PSZ) { lstart[t] = pref[t] - ldeg[t]; lcur[t] = pref[t] - ldeg[t]; }
    __syncthreads();

    // pass B: place src values into per-node runs
    for (int slot = threadIdx.x; slot < BIN_BLOCKS * SCAP; slot += 256) {
        if ((slot & (SCAP - 1)) < cnts[slot / SCAP]) {
            uint e = bin[slot];
            int nd = (int)(e >> 16) - lo;
            int pos = atomicAdd(&lcur[nd], 1);
            if (pos < SORTCAP) sorted[pos] = (ushort)(e & 0xffffu);
        }
    }
    __syncthreads();

    // write-out: per node, vectorized 16B bucket stores + one degree store
    for (int nd = threadIdx.x; nd < nnodes; nd += 256) {
        int st = lstart[nd];
        int cnt = ldeg[nd];
        int node = lo + nd;
        cursor[node * CPAD] = cnt;
        int wcnt = cnt > BUCKET ? BUCKET : cnt;
        ushort* outb = esrc + (size_t)node * BUCKET;
        for (int j = 0; j < wcnt; j += 8) {
            uint w[8];
#pragma unroll
            for (int k = 0; k < 8; ++k) {
                int idx = st + j + k; if (idx >= SORTCAP) idx = SORTCAP - 1;
                w[k] = sorted[idx];
            }
            uint4 v;
            v.x = w[0] | (w[1] << 16);
            v.y = w[2] | (w[3] << 16);
            v.z = w[4] | (w[5] << 16);
            v.w = w[6] | (w[7] << 16);
            *reinterpret_cast<uint4*>(outb + j) = v;   // 128B-aligned base + 16B steps
        }
    }
}

// ---------------- segment mean, bf16 in/out ----------------
// one wave per dst node (50k waves -> max gather TLP); 16 lanes x 16B cover a
// 256B row; 16 edges in flight per iter

__global__ void aggregate_mean_bf16(const ushort* __restrict__ feat, const int* __restrict__ cursor,
                                    const ushort* __restrict__ esrc, ushort* __restrict__ mean, int n) {
    int wid = threadIdx.x >> 6;           // 4 waves per block
    int lane = threadIdx.x & 63;
    int d = blockIdx.x * 4 + wid;
    if (d >= n) return;
    int cnt = cursor[d * CPAD]; if (cnt > BUCKET) cnt = BUCKET;
    int beg = d * BUCKET;
    int g = lane >> 4;                    // edge group 0..3
    int gl = lane & 15;                   // 16B chunk within row

    float acc[8] = {0.f, 0.f, 0.f, 0.f, 0.f, 0.f, 0.f, 0.f};
    for (int i = 0; i < cnt; i += 16) {
        uint4 v[4];
#pragma unroll
        for (int j = 0; j < 4; ++j) {
            int idx = i + g + j * 4;
            v[j] = make_uint4(0u, 0u, 0u, 0u);
            if (idx < cnt) {
                int e = esrc[beg + idx];
                v[j] = ((const uint4*)(feat + (size_t)e * D))[gl];
            }
        }
#pragma unroll
        for (int j = 0; j < 4; ++j) {
            acc[0] += __uint_as_float(v[j].x << 16);
            acc[1] += __uint_as_float(v[j].x & 0xffff0000u);
            acc[2] += __uint_as_float(v[j].y << 16);
            acc[3] += __uint_as_float(v[j].y & 0xffff0000u);
            acc[4] += __uint_as_float(v[j].z << 16);
            acc[5] += __uint_as_float(v[j].z & 0xffff0000u);
            acc[6] += __uint_as_float(v[j].w << 16);
            acc[7] += __uint_as_float(v[j].w & 0xffff0000u);
        }
    }
#pragma unroll
    for (int m = 16; m <= 32; m <<= 1) {
#pragma unroll
        for (int j = 0; j < 8; ++j) acc[j] += __shfl_xor(acc[j], m);
    }
    if (g == 0) {
        float inv = (cnt > 0) ? 1.0f / (float)cnt : 0.0f;
        uint4 o;
        o.x = (uint)f2bf(acc[0] * inv) | ((uint)f2bf(acc[1] * inv) << 16);
        o.y = (uint)f2bf(acc[2] * inv) | ((uint)f2bf(acc[3] * inv) << 16);
        o.z = (uint)f2bf(acc[4] * inv) | ((uint)f2bf(acc[5] * inv) << 16);
        o.w = (uint)f2bf(acc[6] * inv) | ((uint)f2bf(acc[7] * inv) << 16);
        ((uint4*)(mean + (size_t)d * D))[gl] = o;
    }
}

// ---------------- fused SAGE MFMA GEMM: C = [mean|self] @ WT^T + b ----------------
// ONE 16-row tile per wave (no loop, no prefetch -> no spill).
// Swapped operands: mfma(W_frag, Act_frag) -> lane&15 = node, quad = feature.
// Lane's f32x4 acc is feature-contiguous -> 16B f32 / 8B bf16 stores.
// OUTS: fuse out_s = h2 @ Ws via convergent-shfl redistribution + Ws frags in LDS.

template <bool RELU, bool WF32, bool WBF16, bool OUTS>
__global__ __launch_bounds__(512) void sage_mfma(
    const ushort* __restrict__ A1, const ushort* __restrict__ A2,
    const ushort* __restrict__ WTf, const float* __restrict__ bias,
    float* __restrict__ Hf, ushort* __restrict__ Hb,
    const ushort* __restrict__ WsTf, float* __restrict__ OutS)
{
    __shared__ __attribute__((aligned(16))) char smem[OUTS ? 81920 : 65536];
    int w = threadIdx.x >> 6, lane = threadIdx.x & 63;

    // stage WTf linearly (64 KB, fragment-major; dest = uniform base + lane*16)
#pragma unroll
    for (int it = 0; it < 8; ++it) {
        int off = w * 8192 + it * 1024;
        __builtin_amdgcn_global_load_lds(
            (const __attribute__((address_space(1))) void*)((const char*)WTf + off + lane * 16),
            (__attribute__((address_space(3))) void*)(smem + off), 16, 0, 0);
    }
    if (OUTS) {   // stage WsTf (16 KB) at smem+65536
#pragma unroll
        for (int it = 0; it < 2; ++it) {
            int off = w * 2048 + it * 1024;
            __builtin_amdgcn_global_load_lds(
                (const __attribute__((address_space(1))) void*)((const char*)WsTf + off + lane * 16),
                (__attribute__((address_space(3))) void*)(smem + 65536 + off), 16, 0, 0);
        }
    }

    int rl = lane & 15;       // node within tile
    int kg = lane >> 4;       // k-subgroup / feature quad
    int tile = blockIdx.x * 8 + w;

    bf16x8 a[8];
    if (tile < NTILES) {
        const ushort* r1 = A1 + (size_t)(tile * 16 + rl) * 128 + kg * 8;
        const ushort* r2 = A2 + (size_t)(tile * 16 + rl) * 128 + kg * 8;
#pragma unroll
        for (int s = 0; s < 4; ++s) a[s] = *reinterpret_cast<const bf16x8*>(r1 + s * 32);
#pragma unroll
        for (int s = 0; s < 4; ++s) a[4 + s] = *reinterpret_cast<const bf16x8*>(r2 + s * 32);
    }
    __syncthreads();          // staging visible to all waves
    if (tile >= NTILES) return;

    // acc init = bias (broadcast over nodes; lane's features f*16+kg*4..+3)
    f32x4 acc[8];
#pragma unroll
    for (int f = 0; f < 8; ++f)
        acc[f] = *reinterpret_cast<const f32x4*>(bias + f * 16 + kg * 4);

#pragma unroll
    for (int s = 0; s < 8; ++s) {
#pragma unroll
        for (int f = 0; f < 8; ++f) {
            bf16x8 b = *reinterpret_cast<const bf16x8*>(smem + ((f * 8 + s) * 64 + lane) * 16);
            acc[f] = __builtin_amdgcn_mfma_f32_16x16x32_bf16(b, a[s], acc[f], 0, 0, 0);
        }
    }

    int node = tile * 16 + rl;
    // epilogue: lane holds features n = f*16 + kg*4 + (0..3) of `node`
#pragma unroll
    for (int f = 0; f < 8; ++f) {
        f32x4 v = acc[f];
        if (RELU) {
            v[0] = fmaxf(v[0], 0.f); v[1] = fmaxf(v[1], 0.f);
            v[2] = fmaxf(v[2], 0.f); v[3] = fmaxf(v[3], 0.f);
        }
        acc[f] = v;
        size_t o = (size_t)node * 128 + f * 16 + kg * 4;
        if (WF32)
            *reinterpret_cast<f32x4*>(Hf + o) = v;
        if (WBF16) {
            ushort4 ob;
            ob.x = f2bf(v[0]); ob.y = f2bf(v[1]); ob.z = f2bf(v[2]); ob.w = f2bf(v[3]);
            *reinterpret_cast<ushort4*>(Hb + o) = ob;
        }
    }

    if (OUTS) {
        // lane holds bf16(h2) features f*16+kg*4..+3 packed: abx=(e0,e1), aby=(e2,e3)
        uint abx[8], aby[8];
#pragma unroll
        for (int f = 0; f < 8; ++f) {
            abx[f] = (uint)f2bf(acc[f][0]) | ((uint)f2bf(acc[f][1]) << 16);
            aby[f] = (uint)f2bf(acc[f][2]) | ((uint)f2bf(acc[f][3]) << 16);
        }
        int sbase = rl + ((lane & 16) << 1);   // rl + (kg&1)*32
        bool top = lane >= 32;                 // kg>>1
        f32x4 accO[4];
#pragma unroll
        for (int fo = 0; fo < 4; ++fo) accO[fo] = (f32x4){0.f, 0.f, 0.f, 0.f};

#pragma unroll
        for (int s = 0; s < 4; ++s) {
            uint lx = abx[s * 2], ly = aby[s * 2];
            uint hx = abx[s * 2 + 1], hy = aby[s * 2 + 1];
            // CONVERGENT shuffles: all lanes execute every shfl, select after.
            uint l0 = (uint)__shfl((int)lx, sbase);
            uint h0 = (uint)__shfl((int)hx, sbase);
            uint l1 = (uint)__shfl((int)ly, sbase);
            uint h1 = (uint)__shfl((int)hy, sbase);
            uint l2 = (uint)__shfl((int)lx, sbase + 16);
            uint h2_ = (uint)__shfl((int)hx, sbase + 16);
            uint l3 = (uint)__shfl((int)ly, sbase + 16);
            uint h3 = (uint)__shfl((int)hy, sbase + 16);
            uint q0 = top ? h0 : l0;
            uint q1 = top ? h1 : l1;
            uint q2 = top ? h2_ : l2;
            uint q3 = top ? h3 : l3;
            union { uint4 u; bf16x8 b; } cvt;
            cvt.u = make_uint4(q0, q1, q2, q3);
#pragma unroll
            for (int fo = 0; fo < 4; ++fo) {
                bf16x8 wsA = *reinterpret_cast<const bf16x8*>(
                    smem + 65536 + ((fo * 4 + s) * 64 + lane) * 16);
                accO[fo] = __builtin_amdgcn_mfma_f32_16x16x32_bf16(wsA, cvt.b, accO[fo], 0, 0, 0);
            }
        }
#pragma unroll
        for (int fo = 0; fo < 4; ++fo)
            *reinterpret_cast<f32x4*>(OutS + (size_t)node * DS + fo * 16 + kg * 4) = accO[fo];
    }
}

extern "C" void kernel_launch(void* const* d_in, const int* in_sizes, int n_in,
                              void* d_out, int out_size, void* d_ws, size_t ws_size,
                              hipStream_t stream) {
    const float* x   = (const float*)d_in[0];
    const int*   ei  = (const int*)d_in[1];
    const float* Wl1 = (const float*)d_in[2];
    const float* bl1 = (const float*)d_in[3];
    const float* Wr1 = (const float*)d_in[4];
    const float* Wl2 = (const float*)d_in[5];
    const float* bl2 = (const float*)d_in[6];
    const float* Wr2 = (const float*)d_in[7];
    const float* Ws  = (const float*)d_in[8];

    const int* src = ei;              // edge_index[0]
    const int* dst = ei + E_EDGES;    // edge_index[1]

    char* wsb = (char*)d_ws;
    size_t off = 0;
    auto alloc = [&](size_t bytes) -> void* {
        void* p = wsb + off;
        off = (off + bytes + 255) & ~(size_t)255;
        return p;
    };
    int*    cursor = (int*)alloc(4 * (size_t)N_NODES * CPAD);
    int*    bincnt = (int*)alloc(4 * (size_t)NPART2 * BIN_BLOCKS);
    uint*   binned = (uint*)alloc(4 * (size_t)NPART2 * BIN_BLOCKS * SCAP);
    ushort* esrc   = (ushort*)alloc(2 * (size_t)N_NODES * BUCKET);
    ushort* xb     = (ushort*)alloc(2 * (size_t)N_NODES * D);
    ushort* meanb  = (ushort*)alloc(2 * (size_t)N_NODES * D);
    ushort* h1b    = (ushort*)alloc(2 * (size_t)N_NODES * D);
    ushort* WT1f   = (ushort*)alloc(2 * 128 * 256);
    ushort* WT2f   = (ushort*)alloc(2 * 128 * 256);
    ushort* WsTf   = (ushort*)alloc(2 * 64 * 128);

    float* out_s = (float*)d_out;
    float* h2    = (float*)d_out + (size_t)N_NODES * DS;

    // prep (x->bf16 + weight transposes); cursor fully written by sort_pass
    prep_kernel<<<2048, 256, 0, stream>>>(x, Wl1, Wr1, Wl2, Wr2, Ws,
                                          xb, WT1f, WT2f, WsTf);

    // CSR build: LDS binning (coalesced) + per-partition LDS counting sort
    bin_pass<<<BIN_BLOCKS, 256, 0, stream>>>(src, dst, bincnt, binned);
    sort_pass<<<NPART2, 256, 0, stream>>>(binned, bincnt, cursor, esrc);

    const int GB = (NTILES + 7) / 8;  // 391 blocks, one 16-row tile per wave

    // layer 1
    aggregate_mean_bf16<<<(N_NODES + 3) / 4, 256, 0, stream>>>(xb, cursor, esrc, meanb, N_NODES);
    sage_mfma<true, false, true, false><<<GB, 512, 0, stream>>>(
        meanb, xb, WT1f, bl1, nullptr, h1b, nullptr, nullptr);

    // layer 2 (+ fused out_s)
    aggregate_mean_bf16<<<(N_NODES + 3) / 4, 256, 0, stream>>>(h1b, cursor, esrc, meanb, N_NODES);
    sage_mfma<false, true, false, true><<<GB, 512, 0, stream>>>(
        meanb, h1b, WT2f, bl2, h2, nullptr, WsTf, out_s);
}

// Round 20
// 124.724 us; speedup vs baseline: 3.5160x; 1.0157x over previous
//
#include <hip/hip_runtime.h>

#define N_NODES 50000
#define E_EDGES 640000
#define D 128
#define DS 64
#define NTILES 3125   // 50000 / 16 exactly
#define BUCKET 64     // max degree capacity (Poisson(12.8): P(>64) ~ 0)
#define CPAD 16       // one cursor counter per 64B line
#define NPART 8       // dst-range partitions (~XCDs)
#define PSIZE 6250    // N_NODES / NPART

typedef __bf16 bf16x8 __attribute__((ext_vector_type(8)));
typedef float f32x4 __attribute__((ext_vector_type(4)));

static __device__ __forceinline__ ushort f2bf(float f) {
    uint u = __float_as_uint(f);
    uint r = u + 0x7fffu + ((u >> 16) & 1u);
    return (ushort)(r >> 16);
}

// ---------------- fused prep: zero cursor + x->bf16 + weight transposes ----------------
// Fragment-major weight layouts.
// WTf: fragment (f=n/16, s=k/32): F=f*8+s; lane l=(n&15)|(((k>>3)&3)<<4);
//      (n,k) -> WTf[(F*64+l)*8+(k&7)].  WsTf: F=(m>>4)*4+(k>>5), same inner.

__global__ void prep_kernel(const float* __restrict__ x,
                            const float* __restrict__ Wl1, const float* __restrict__ Wr1,
                            const float* __restrict__ Wl2, const float* __restrict__ Wr2,
                            const float* __restrict__ Ws,
                            int* __restrict__ cursor, ushort* __restrict__ xb,
                            ushort* __restrict__ WT1f, ushort* __restrict__ WT2f,
                            ushort* __restrict__ WsTf) {
    int tid = blockIdx.x * blockDim.x + threadIdx.x;
    int stride = gridDim.x * blockDim.x;
    for (int i = tid; i < N_NODES * CPAD; i += stride) cursor[i] = 0;
    if (tid < 32768) {
        int n = tid >> 8, k = tid & 255;
        float v = (k < 128) ? Wl1[k * 128 + n] : Wr1[(k - 128) * 128 + n];
        int F = (n >> 4) * 8 + (k >> 5);
        int l = (n & 15) | (((k >> 3) & 3) << 4);
        WT1f[(F * 64 + l) * 8 + (k & 7)] = f2bf(v);
    } else if (tid < 65536) {
        int j = tid - 32768;
        int n = j >> 8, k = j & 255;
        float v = (k < 128) ? Wl2[k * 128 + n] : Wr2[(k - 128) * 128 + n];
        int F = (n >> 4) * 8 + (k >> 5);
        int l = (n & 15) | (((k >> 3) & 3) << 4);
        WT2f[(F * 64 + l) * 8 + (k & 7)] = f2bf(v);
    } else if (tid < 73728) {
        int j = tid - 65536;
        int m = j >> 7, k = j & 127;
        int F = (m >> 4) * 4 + (k >> 5);
        int l = (m & 15) | (((k >> 3) & 3) << 4);
        WsTf[(F * 64 + l) * 8 + (k & 7)] = f2bf(Ws[k * 64 + m]);
    }
    const int n4 = N_NODES * D / 4;
    for (int i = tid; i < n4; i += stride) {
        float4 v = ((const float4*)x)[i];
        ushort4 o;
        o.x = f2bf(v.x); o.y = f2bf(v.y); o.z = f2bf(v.z); o.w = f2bf(v.w);
        ((ushort4*)xb)[i] = o;
    }
}

// ---------------- partitioned single-pass bucket fill ----------------
// Group g = blockIdx&7 handles dst range [g*PSIZE,(g+1)*PSIZE): all writes
// to a node's bucket come from one group in one pass. Line-padded cursor.

__global__ void fill_part(const int* __restrict__ src, const int* __restrict__ dst,
                          int* __restrict__ cursor, ushort* __restrict__ esrc, int e) {
    int g = blockIdx.x & (NPART - 1);     // partition / ~XCD (round-robin heuristic)
    int bchunk = blockIdx.x >> 3;         // block within group
    int lo = g * PSIZE, hi = lo + PSIZE;
    int nb = gridDim.x >> 3;
    int i = bchunk * blockDim.x + threadIdx.x;
    int stride = nb * blockDim.x;
    for (; i < e; i += stride) {
        int d = dst[i];
        if (d >= lo && d < hi) {
            int pos = atomicAdd(&cursor[d * CPAD], 1);
            if (pos < BUCKET) esrc[d * BUCKET + pos] = (ushort)src[i];
        }
    }
}

// ---------------- segment mean, bf16 in/out ----------------
// one wave per dst node (50k waves -> max gather TLP); 16 lanes x 16B cover a
// 256B row; 16 edges in flight per iter

__global__ void aggregate_mean_bf16(const ushort* __restrict__ feat, const int* __restrict__ cursor,
                                    const ushort* __restrict__ esrc, ushort* __restrict__ mean, int n) {
    int wid = threadIdx.x >> 6;           // 4 waves per block
    int lane = threadIdx.x & 63;
    int d = blockIdx.x * 4 + wid;
    if (d >= n) return;
    int cnt = cursor[d * CPAD]; if (cnt > BUCKET) cnt = BUCKET;
    int beg = d * BUCKET;
    int g = lane >> 4;                    // edge group 0..3
    int gl = lane & 15;                   // 16B chunk within row

    float acc[8] = {0.f, 0.f, 0.f, 0.f, 0.f, 0.f, 0.f, 0.f};
    for (int i = 0; i < cnt; i += 16) {
        uint4 v[4];
#pragma unroll
        for (int j = 0; j < 4; ++j) {
            int idx = i + g + j * 4;
            v[j] = make_uint4(0u, 0u, 0u, 0u);
            if (idx < cnt) {
                int e = esrc[beg + idx];
                v[j] = ((const uint4*)(feat + (size_t)e * D))[gl];
            }
        }
#pragma unroll
        for (int j = 0; j < 4; ++j) {
            acc[0] += __uint_as_float(v[j].x << 16);
            acc[1] += __uint_as_float(v[j].x & 0xffff0000u);
            acc[2] += __uint_as_float(v[j].y << 16);
            acc[3] += __uint_as_float(v[j].y & 0xffff0000u);
            acc[4] += __uint_as_float(v[j].z << 16);
            acc[5] += __uint_as_float(v[j].z & 0xffff0000u);
            acc[6] += __uint_as_float(v[j].w << 16);
            acc[7] += __uint_as_float(v[j].w & 0xffff0000u);
        }
    }
#pragma unroll
    for (int m = 16; m <= 32; m <<= 1) {
#pragma unroll
        for (int j = 0; j < 8; ++j) acc[j] += __shfl_xor(acc[j], m);
    }
    if (g == 0) {
        float inv = (cnt > 0) ? 1.0f / (float)cnt : 0.0f;
        uint4 o;
        o.x = (uint)f2bf(acc[0] * inv) | ((uint)f2bf(acc[1] * inv) << 16);
        o.y = (uint)f2bf(acc[2] * inv) | ((uint)f2bf(acc[3] * inv) << 16);
        o.z = (uint)f2bf(acc[4] * inv) | ((uint)f2bf(acc[5] * inv) << 16);
        o.w = (uint)f2bf(acc[6] * inv) | ((uint)f2bf(acc[7] * inv) << 16);
        ((uint4*)(mean + (size_t)d * D))[gl] = o;
    }
}

// ---------------- fused SAGE MFMA GEMM: C = [mean|self] @ WT^T + b ----------------
// ONE 16-row tile per wave (no loop, no prefetch -> no spill).
// Swapped operands: mfma(W_frag, Act_frag) -> lane&15 = node, quad = feature.
// Lane's f32x4 acc is feature-contiguous -> 16B f32 / 8B bf16 stores.
// OUTS: fuse out_s = h2 @ Ws via convergent-shfl redistribution + Ws frags in LDS.

template <bool RELU, bool WF32, bool WBF16, bool OUTS>
__global__ __launch_bounds__(512) void sage_mfma(
    const ushort* __restrict__ A1, const ushort* __restrict__ A2,
    const ushort* __restrict__ WTf, const float* __restrict__ bias,
    float* __restrict__ Hf, ushort* __restrict__ Hb,
    const ushort* __restrict__ WsTf, float* __restrict__ OutS)
{
    __shared__ __attribute__((aligned(16))) char smem[OUTS ? 81920 : 65536];
    int w = threadIdx.x >> 6, lane = threadIdx.x & 63;

    // stage WTf linearly (64 KB, fragment-major; dest = uniform base + lane*16)
#pragma unroll
    for (int it = 0; it < 8; ++it) {
        int off = w * 8192 + it * 1024;
        __builtin_amdgcn_global_load_lds(
            (const __attribute__((address_space(1))) void*)((const char*)WTf + off + lane * 16),
            (__attribute__((address_space(3))) void*)(smem + off), 16, 0, 0);
    }
    if (OUTS) {   // stage WsTf (16 KB) at smem+65536
#pragma unroll
        for (int it = 0; it < 2; ++it) {
            int off = w * 2048 + it * 1024;
            __builtin_amdgcn_global_load_lds(
                (const __attribute__((address_space(1))) void*)((const char*)WsTf + off + lane * 16),
                (__attribute__((address_space(3))) void*)(smem + 65536 + off), 16, 0, 0);
        }
    }

    int rl = lane & 15;       // node within tile
    int kg = lane >> 4;       // k-subgroup / feature quad
    int tile = blockIdx.x * 8 + w;

    bf16x8 a[8];
    if (tile < NTILES) {
        const ushort* r1 = A1 + (size_t)(tile * 16 + rl) * 128 + kg * 8;
        const ushort* r2 = A2 + (size_t)(tile * 16 + rl) * 128 + kg * 8;
#pragma unroll
        for (int s = 0; s < 4; ++s) a[s] = *reinterpret_cast<const bf16x8*>(r1 + s * 32);
#pragma unroll
        for (int s = 0; s < 4; ++s) a[4 + s] = *reinterpret_cast<const bf16x8*>(r2 + s * 32);
    }
    __syncthreads();          // staging visible to all waves
    if (tile >= NTILES) return;

    // acc init = bias (broadcast over nodes; lane's features f*16+kg*4..+3)
    f32x4 acc[8];
#pragma unroll
    for (int f = 0; f < 8; ++f)
        acc[f] = *reinterpret_cast<const f32x4*>(bias + f * 16 + kg * 4);

#pragma unroll
    for (int s = 0; s < 8; ++s) {
#pragma unroll
        for (int f = 0; f < 8; ++f) {
            bf16x8 b = *reinterpret_cast<const bf16x8*>(smem + ((f * 8 + s) * 64 + lane) * 16);
            acc[f] = __builtin_amdgcn_mfma_f32_16x16x32_bf16(b, a[s], acc[f], 0, 0, 0);
        }
    }

    int node = tile * 16 + rl;
    // epilogue: lane holds features n = f*16 + kg*4 + (0..3) of `node`
#pragma unroll
    for (int f = 0; f < 8; ++f) {
        f32x4 v = acc[f];
        if (RELU) {
            v[0] = fmaxf(v[0], 0.f); v[1] = fmaxf(v[1], 0.f);
            v[2] = fmaxf(v[2], 0.f); v[3] = fmaxf(v[3], 0.f);
        }
        acc[f] = v;
        size_t o = (size_t)node * 128 + f * 16 + kg * 4;
        if (WF32)
            *reinterpret_cast<f32x4*>(Hf + o) = v;
        if (WBF16) {
            ushort4 ob;
            ob.x = f2bf(v[0]); ob.y = f2bf(v[1]); ob.z = f2bf(v[2]); ob.w = f2bf(v[3]);
            *reinterpret_cast<ushort4*>(Hb + o) = ob;
        }
    }

    if (OUTS) {
        // lane holds bf16(h2) features f*16+kg*4..+3 packed: abx=(e0,e1), aby=(e2,e3)
        uint abx[8], aby[8];
#pragma unroll
        for (int f = 0; f < 8; ++f) {
            abx[f] = (uint)f2bf(acc[f][0]) | ((uint)f2bf(acc[f][1]) << 16);
            aby[f] = (uint)f2bf(acc[f][2]) | ((uint)f2bf(acc[f][3]) << 16);
        }
        int sbase = rl + ((lane & 16) << 1);   // rl + (kg&1)*32
        bool top = lane >= 32;                 // kg>>1
        f32x4 accO[4];
#pragma unroll
        for (int fo = 0; fo < 4; ++fo) accO[fo] = (f32x4){0.f, 0.f, 0.f, 0.f};

#pragma unroll
        for (int s = 0; s < 4; ++s) {
            uint lx = abx[s * 2], ly = aby[s * 2];
            uint hx = abx[s * 2 + 1], hy = aby[s * 2 + 1];
            // CONVERGENT shuffles: all lanes execute every shfl, select after.
            uint l0 = (uint)__shfl((int)lx, sbase);
            uint h0 = (uint)__shfl((int)hx, sbase);
            uint l1 = (uint)__shfl((int)ly, sbase);
            uint h1 = (uint)__shfl((int)hy, sbase);
            uint l2 = (uint)__shfl((int)lx, sbase + 16);
            uint h2_ = (uint)__shfl((int)hx, sbase + 16);
            uint l3 = (uint)__shfl((int)ly, sbase + 16);
            uint h3 = (uint)__shfl((int)hy, sbase + 16);
            uint q0 = top ? h0 : l0;
            uint q1 = top ? h1 : l1;
            uint q2 = top ? h2_ : l2;
            uint q3 = top ? h3 : l3;
            union { uint4 u; bf16x8 b; } cvt;
            cvt.u = make_uint4(q0, q1, q2, q3);
#pragma unroll
            for (int fo = 0; fo < 4; ++fo) {
                bf16x8 wsA = *reinterpret_cast<const bf16x8*>(
                    smem + 65536 + ((fo * 4 + s) * 64 + lane) * 16);
                accO[fo] = __builtin_amdgcn_mfma_f32_16x16x32_bf16(wsA, cvt.b, accO[fo], 0, 0, 0);
            }
        }
#pragma unroll
        for (int fo = 0; fo < 4; ++fo)
            *reinterpret_cast<f32x4*>(OutS + (size_t)node * DS + fo * 16 + kg * 4) = accO[fo];
    }
}

extern "C" void kernel_launch(void* const* d_in, const int* in_sizes, int n_in,
                              void* d_out, int out_size, void* d_ws, size_t ws_size,
                              hipStream_t stream) {
    const float* x   = (const float*)d_in[0];
    const int*   ei  = (const int*)d_in[1];
    const float* Wl1 = (const float*)d_in[2];
    const float* bl1 = (const float*)d_in[3];
    const float* Wr1 = (const float*)d_in[4];
    const float* Wl2 = (const float*)d_in[5];
    const float* bl2 = (const float*)d_in[6];
    const float* Wr2 = (const float*)d_in[7];
    const float* Ws  = (const float*)d_in[8];

    const int* src = ei;              // edge_index[0]
    const int* dst = ei + E_EDGES;    // edge_index[1]

    char* wsb = (char*)d_ws;
    size_t off = 0;
    auto alloc = [&](size_t bytes) -> void* {
        void* p = wsb + off;
        off = (off + bytes + 255) & ~(size_t)255;
        return p;
    };
    int*    cursor = (int*)alloc(4 * (size_t)N_NODES * CPAD);
    ushort* esrc   = (ushort*)alloc(2 * (size_t)N_NODES * BUCKET);
    ushort* xb     = (ushort*)alloc(2 * (size_t)N_NODES * D);
    ushort* meanb  = (ushort*)alloc(2 * (size_t)N_NODES * D);
    ushort* h1b    = (ushort*)alloc(2 * (size_t)N_NODES * D);
    ushort* WT1f   = (ushort*)alloc(2 * 128 * 256);
    ushort* WT2f   = (ushort*)alloc(2 * 128 * 256);
    ushort* WsTf   = (ushort*)alloc(2 * 64 * 128);

    float* out_s = (float*)d_out;
    float* h2    = (float*)d_out + (size_t)N_NODES * DS;

    // prep (zero cursor + x->bf16 + weight transposes)
    prep_kernel<<<2048, 256, 0, stream>>>(x, Wl1, Wr1, Wl2, Wr2, Ws,
                                          cursor, xb, WT1f, WT2f, WsTf);

    // partitioned single-pass bucket CSR (1024 blocks = 8 groups x 128)
    fill_part<<<1024, 256, 0, stream>>>(src, dst, cursor, esrc, E_EDGES);

    const int GB = (NTILES + 7) / 8;  // 391 blocks, one 16-row tile per wave

    // layer 1
    aggregate_mean_bf16<<<(N_NODES + 3) / 4, 256, 0, stream>>>(xb, cursor, esrc, meanb, N_NODES);
    sage_mfma<true, false, true, false><<<GB, 512, 0, stream>>>(
        meanb, xb, WT1f, bl1, nullptr, h1b, nullptr, nullptr);

    // layer 2 (+ fused out_s)
    aggregate_mean_bf16<<<(N_NODES + 3) / 4, 256, 0, stream>>>(h1b, cursor, esrc, meanb, N_NODES);
    sage_mfma<false, true, false, true><<<GB, 512, 0, stream>>>(
        meanb, h1b, WT2f, bl2, h2, nullptr, WsTf, out_s);
}